// Round 1
// baseline (217.718 us; speedup 1.0000x reference)
//
#include <hip/hip_runtime.h>

// Rainfusion blockwise sparse attention. f32 in/out; fp16 MFMA inside.
// Fixed-m softmax (m=0). Prep pre-permutes K,V to padded fp16 tiles (coalesced).
// Flash: selection fused (wave 0 per light wg); h = blockIdx%8 for XCD-L2 affinity.
// R1: software-pipelined staging — double-buffered Ks/Vsh, counted vmcnt(9),
//     raw s_barrier (no compiler vmcnt(0) drain), setprio around MFMA clusters.
//     VROW 72->68 so K and V tiles are both 17x1KB chunks (9 loads/wave/tile).
//     combine regridded 96->768 blocks.

typedef __attribute__((ext_vector_type(8))) _Float16 half8;
typedef __attribute__((ext_vector_type(4))) _Float16 half4;
typedef __attribute__((ext_vector_type(4))) float float4v;

#define KROW 136   // shorts per K row: 128 dims + 8 pad (stride 68 dwords, conflict-free)
#define VROW 68    // shorts per V^T row: 64 toks + 4 pad (stride 34 dwords, conflict-free)
#define PROW 72

__device__ __forceinline__ int orig_pos(int j) {
    if (j >= 3840) return (j < 4224) ? (j - 3840) : j;
    int blk = j >> 7;
    int r   = j & 127;
    int f   = blk / 6;
    int rem = blk - f * 6;
    int b2  = rem / 3;
    int e   = rem - b2 * 3;
    int a   = r >> 6;
    int c   = (r >> 3) & 7;
    int g   = r & 7;
    return 384 + (f * 2 + a) * 384 + (b2 * 8 + c) * 24 + e * 8 + g;
}

__device__ __forceinline__ void cp16(const void* g, void* l) {
    __builtin_amdgcn_global_load_lds((const __attribute__((address_space(1))) void*)g,
                                     (__attribute__((address_space(3))) void*)l, 16, 0, 0);
}

// ---------------- prep: grid 576 = (h, kb, sub). conv 64 toks + one pooled sum ----------------
__global__ __launch_bounds__(256) void prep_kernel(const float* __restrict__ q,
                                                   const float* __restrict__ k,
                                                   const float* __restrict__ v,
                                                   short* __restrict__ Kc,
                                                   unsigned* __restrict__ Vt32,
                                                   float* __restrict__ qp,
                                                   float* __restrict__ kp) {
    __shared__ short Vs[64 * KROW];
    __shared__ float Rs[8 * 128];
    int bx  = blockIdx.x;
    int tid = threadIdx.x;
    int sub = bx & 1;
    int kb  = (bx >> 1) % 36;
    int h   = bx / 72;

    { // conv: 64 toks -> Kc fp16 + Vs (LDS). Coalesced: 8 lanes x consecutive float4 per row.
        int lr = tid >> 3;             // row group 0..31
        int ld = (tid & 7) << 2;       // float offset 0..28
#pragma unroll
        for (int pass = 0; pass < 2; ++pass) {
            int lt  = pass * 32 + lr;  // local tok 0..63
            int tok = sub * 64 + lt;
            int op  = orig_pos(kb * 128 + tok);
            const float* kr = k + ((size_t)op * 8 + h) * 128;
            const float* vr = v + ((size_t)op * 8 + h) * 128;
            short* ko = Kc + ((size_t)(h * 36 + kb) * 128 + tok) * KROW;
#pragma unroll
            for (int j = 0; j < 4; ++j) {
                int d = ld + j * 32;
                float4v xk = *reinterpret_cast<const float4v*>(kr + d);
                float4v xv = *reinterpret_cast<const float4v*>(vr + d);
                half4 hk, hv;
#pragma unroll
                for (int i = 0; i < 4; ++i) { hk[i] = (_Float16)xk[i]; hv[i] = (_Float16)xv[i]; }
                *reinterpret_cast<half4*>(ko + d) = hk;
                *reinterpret_cast<half4*>(&Vs[lt * KROW + d]) = hv;
            }
        }
    }

    { // pooled sum over the full 128-token block: sub=0 -> K, sub=1 -> Q (already coalesced)
        const float* arr = sub ? q : k;
        int dq = (tid & 31) << 2;
        int g  = tid >> 5;
        float4v acc = {0.f, 0.f, 0.f, 0.f};
        for (int t = g; t < 128; t += 8) {
            int op = orig_pos(kb * 128 + t);
            float4v x = *reinterpret_cast<const float4v*>(arr + ((size_t)op * 8 + h) * 128 + dq);
            acc[0] += x[0]; acc[1] += x[1]; acc[2] += x[2]; acc[3] += x[3];
        }
#pragma unroll
        for (int i = 0; i < 4; ++i) Rs[g * 128 + dq + i] = acc[i];
    }
    __syncthreads();

    { // V^T -> Vt [h][kb][sub][dim][VROW/2], dword-packed token pairs
        const unsigned short* Vsu = (const unsigned short*)Vs;
        unsigned* vo = Vt32 + (size_t)((h * 36 + kb) * 2 + sub) * 128 * (VROW / 2);
#pragma unroll
        for (int it = 0; it < 16; ++it) {
            int i   = it * 256 + tid;
            int tw  = i & 31;
            int dim = i >> 5;
            unsigned lo = Vsu[(2 * tw) * KROW + dim];
            unsigned hi = Vsu[(2 * tw + 1) * KROW + dim];
            vo[dim * (VROW / 2) + tw] = (hi << 16) | lo;
        }
    }

    if (tid < 128) { // reduce 8 groups -> pooled mean
        float s = 0.f;
#pragma unroll
        for (int g = 0; g < 8; ++g) s += Rs[g * 128 + tid];
        float* outp = sub ? qp : kp;
        outp[(h * 36 + kb) * 128 + tid] = s * (1.f / 128.f);
    }
}

// stage one (kb,sub) tile into LDS double-buffer slot. 34 real 1KB chunks:
// 17 K + 17 V; waves 0,1 issue 9, waves 2,3 issue 8 + 1 benign duplicate -> 9 each.
__device__ __forceinline__ void stage_tile(const short* __restrict__ Kc,
                                           const short* __restrict__ Vt,
                                           int h, int kb, int sub,
                                           int wave, int lane,
                                           char* lK, char* lV) {
    const char* gK = (const char*)(Kc + ((size_t)((h * 36 + kb) * 128) + sub * 64) * KROW);
    const char* gV = (const char*)(Vt + (size_t)((h * 36 + kb) * 2 + sub) * 128 * VROW);
    int off = lane * 16;
    for (int c = wave; c < 34; c += 4) {
        if (c < 17) cp16(gK + c * 1024 + off, lK + c * 1024 + off);
        else        cp16(gV + (c - 17) * 1024 + off, lV + (c - 17) * 1024 + off);
    }
    if (wave >= 2) cp16(gK + wave * 1024 + off, lK + wave * 1024 + off);  // equalize vmcnt
}

// ---------------- flash ----------------
// grid 768, h = blockIdx%8 (XCD affinity). 0..287 heavy (h + 8*(qbh*6+half*3+chunk)),
// 288..767 light (h + 8*(qb*2+half)). Light wgs self-select (wave 0), no select kernel.
// LDS 79KB -> 2 wg/CU; staging pipelined 2 tiles deep with counted vmcnt.
__global__ __launch_bounds__(256, 2) void flash_kernel(const float* __restrict__ q,
                                                       const short* __restrict__ Kc,
                                                       const short* __restrict__ Vt,
                                                       const float* __restrict__ qp,
                                                       const float* __restrict__ kp,
                                                       float* __restrict__ out,
                                                       float* __restrict__ pO,
                                                       float* __restrict__ pL) {
    __shared__ __align__(16) short Ks[2][64 * KROW];    // 2 x 17408 B
    __shared__ __align__(16) short Vsh[2][128 * VROW];  // 2 x 17408 B
    __shared__ __align__(16) short Ph[4 * 16 * PROW];   // 9216 B
    __shared__ int Ls[40];

    int t = blockIdx.x;
    int h, qb, half, nkb = 0, kbase = 0, pidx = -1;
    if (t < 288) {
        h = t & 7;
        int rest = t >> 3;             // 0..35 = qbh*6 + half*3 + chunk
        int qbh = rest / 6, r2 = rest % 6;
        half = r2 / 3;
        int chunk = r2 % 3;
        qb = 30 + qbh; nkb = 12; kbase = chunk * 12; pidx = t;
    } else {
        int t2 = t - 288;
        h = t2 & 7;
        int rest = t2 >> 3;            // 0..59 = qb*2 + half
        qb = rest >> 1; half = rest & 1;
    }

    int tid = threadIdx.x, wave = tid >> 6, lane = tid & 63;
    int m16 = lane & 15, quad = lane >> 4;

    // Q A-frags: once per task
    int qrow_frag = qb * 128 + half * 64 + wave * 16 + m16;
    const float* qrp = q + ((size_t)orig_pos(qrow_frag) * 8 + h) * 128;
    half8 aq[4];
#pragma unroll
    for (int kc = 0; kc < 4; ++kc) {
        float4v x0 = *reinterpret_cast<const float4v*>(qrp + kc * 32 + quad * 8);
        float4v x1 = *reinterpret_cast<const float4v*>(qrp + kc * 32 + quad * 8 + 4);
#pragma unroll
        for (int j = 0; j < 4; ++j) { aq[kc][j] = (_Float16)x0[j]; aq[kc][4 + j] = (_Float16)x1[j]; }
    }

    // fused selection (light tasks only; wave 0) — identical arithmetic to old select_kernel
    if (pidx < 0 && wave == 0) {
        float s = -1e30f;
        if (lane < 36) {
            const float4v* qv = (const float4v*)(qp + (h * 36 + qb) * 128);
            const float4v* kv = (const float4v*)(kp + (h * 36 + lane) * 128);
            float acc = 0.f;
            for (int i = 0; i < 32; ++i) {
                float4v a = qv[i], b = kv[i];
                acc += a[0] * b[0] + a[1] * b[1] + a[2] * b[2] + a[3] * b[3];
            }
            s = acc;
        }
        float tmp = s;
        float thr = 0.f;
        for (int i = 0; i < 4; ++i) {
            float mx = tmp;
            for (int off = 1; off < 64; off <<= 1) mx = fmaxf(mx, __shfl_xor(mx, off));
            thr = mx;
            unsigned long long bal = __ballot(tmp == mx);
            int low = __ffsll(bal) - 1;
            if (lane == low) tmp = -3e38f;
        }
        bool keep = (lane < 36) && ((s >= thr) || (lane >= 30));
        unsigned long long mk = __ballot(keep);
        if (lane == 0) Ls[0] = __popcll(mk);
        if (keep) {
            int pos = __popcll(mk & ((1ull << lane) - 1ull));
            Ls[1 + pos] = lane;
        }
    }
    __syncthreads();
    if (pidx < 0) nkb = Ls[0];

    float l_r[4], o[8][4];
#pragma unroll
    for (int r = 0; r < 4; ++r) l_r[r] = 0.f;
#pragma unroll
    for (int dt = 0; dt < 8; ++dt)
#pragma unroll
        for (int r = 0; r < 4; ++r) o[dt][r] = 0.f;

    constexpr float kScale = 0.08838834764831845f * 1.4426950408889634f;
    short* Phw = Ph + wave * (16 * PROW);

    int ntile = nkb * 2;

    // prologue: stage tiles 0 and 1 (same kb, sub 0/1; ntile >= 12 always)
    {
        int kb0 = (pidx >= 0) ? kbase : Ls[1];
        stage_tile(Kc, Vt, h, kb0, 0, wave, lane, (char*)&Ks[0][0], (char*)&Vsh[0][0]);
        stage_tile(Kc, Vt, h, kb0, 1, wave, lane, (char*)&Ks[1][0], (char*)&Vsh[1][0]);
    }

    for (int it = 0; it < ntile; ++it) {
        int cur = it & 1;
        // counted wait: tile it's 9 loads done; tile it+1's 9 may still fly.
        if (it + 1 < ntile) { asm volatile("s_waitcnt vmcnt(9)" ::: "memory"); }
        else                { asm volatile("s_waitcnt vmcnt(0)" ::: "memory"); }
        __builtin_amdgcn_s_barrier();          // all waves' tile-it data resident
        __builtin_amdgcn_sched_barrier(0);

        // S = Q K^T (64 tokens)
        float4v sacc[4];
#pragma unroll
        for (int nt = 0; nt < 4; ++nt) { sacc[nt][0] = 0.f; sacc[nt][1] = 0.f; sacc[nt][2] = 0.f; sacc[nt][3] = 0.f; }
        __builtin_amdgcn_s_setprio(1);
#pragma unroll
        for (int nt = 0; nt < 4; ++nt)
#pragma unroll
            for (int kc = 0; kc < 4; ++kc) {
                half8 bk = *reinterpret_cast<const half8*>(&Ks[cur][(nt * 16 + m16) * KROW + kc * 32 + quad * 8]);
                sacc[nt] = __builtin_amdgcn_mfma_f32_16x16x32_f16(aq[kc], bk, sacc[nt], 0, 0, 0);
            }
        __builtin_amdgcn_s_setprio(0);

        // fixed-m softmax: p = 2^(s*scale); lane-local l accumulation
#pragma unroll
        for (int r = 0; r < 4; ++r) {
            float p0 = exp2f(sacc[0][r] * kScale);
            float p1 = exp2f(sacc[1][r] * kScale);
            float p2 = exp2f(sacc[2][r] * kScale);
            float p3 = exp2f(sacc[3][r] * kScale);
            sacc[0][r] = p0; sacc[1][r] = p1; sacc[2][r] = p2; sacc[3][r] = p3;
            l_r[r] += (p0 + p1) + (p2 + p3);
        }

        // P -> fp16 LDS (wave-private; C-layout write, A-layout read)
#pragma unroll
        for (int nt = 0; nt < 4; ++nt)
#pragma unroll
            for (int r = 0; r < 4; ++r) {
                union { _Float16 hf; short s; } cv;
                cv.hf = (_Float16)sacc[nt][r];
                Phw[(quad * 4 + r) * PROW + nt * 16 + m16] = cv.s;
            }
        half8 ap0 = *reinterpret_cast<const half8*>(&Phw[m16 * PROW + quad * 8]);
        half8 ap1 = *reinterpret_cast<const half8*>(&Phw[m16 * PROW + 32 + quad * 8]);

        __builtin_amdgcn_s_setprio(1);
#pragma unroll
        for (int dt = 0; dt < 8; ++dt) {
            float4v oc;
            oc[0] = o[dt][0]; oc[1] = o[dt][1]; oc[2] = o[dt][2]; oc[3] = o[dt][3];
            half8 bv0 = *reinterpret_cast<const half8*>(&Vsh[cur][(dt * 16 + m16) * VROW + quad * 8]);
            half8 bv1 = *reinterpret_cast<const half8*>(&Vsh[cur][(dt * 16 + m16) * VROW + 32 + quad * 8]);
            oc = __builtin_amdgcn_mfma_f32_16x16x32_f16(ap0, bv0, oc, 0, 0, 0);
            oc = __builtin_amdgcn_mfma_f32_16x16x32_f16(ap1, bv1, oc, 0, 0, 0);
            o[dt][0] = oc[0]; o[dt][1] = oc[1]; o[dt][2] = oc[2]; o[dt][3] = oc[3];
        }
        __builtin_amdgcn_s_setprio(0);

        __builtin_amdgcn_sched_barrier(0);
        __builtin_amdgcn_s_barrier();          // all waves done reading buf[cur]
        if (it + 2 < ntile) {                  // refill buf[cur] with tile it+2
            int it2 = it + 2;
            int kb2 = (pidx >= 0) ? (kbase + (it2 >> 1)) : Ls[1 + (it2 >> 1)];
            stage_tile(Kc, Vt, h, kb2, it2 & 1, wave, lane, (char*)&Ks[cur][0], (char*)&Vsh[cur][0]);
        }
    }

    // epilogue: reduce l across the quad's 16 lanes
#pragma unroll
    for (int r = 0; r < 4; ++r)
        for (int sh = 1; sh < 16; sh <<= 1) l_r[r] += __shfl_xor(l_r[r], sh);

    if (pidx >= 0) {
        float* po = pO + (size_t)pidx * 8192;
#pragma unroll
        for (int r = 0; r < 4; ++r) {
            int row = wave * 16 + quad * 4 + r;
#pragma unroll
            for (int dt = 0; dt < 8; ++dt)
                po[row * 128 + dt * 16 + m16] = o[dt][r];
            if (m16 == 0) pL[pidx * 64 + row] = l_r[r];
        }
    } else {
#pragma unroll
        for (int r = 0; r < 4; ++r) {
            int qrow = qb * 128 + half * 64 + wave * 16 + quad * 4 + r;
            size_t base = ((size_t)orig_pos(qrow) * 8 + h) * 128;
            float inv = 1.f / l_r[r];
#pragma unroll
            for (int dt = 0; dt < 8; ++dt)
                out[base + dt * 16 + m16] = o[dt][r] * inv;
        }
    }
}

// ---------------- combine (heavy only; fixed-m partials sum linearly) ----------------
// regridded: 768 blocks = 96 groups x 8 row-groups (was 96 blocks, 0.375/CU, latency-bound)
__global__ void combine_kernel(const float* __restrict__ pO, const float* __restrict__ pL,
                               float* __restrict__ out) {
    int gb = blockIdx.x;             // 768
    int g  = gb >> 3;                // 96 = (h,qbh,half)
    int rg = gb & 7;                 // row-group: 8 rows each
    int h    = g / 12;
    int rem  = g % 12;
    int qbh  = rem >> 1;
    int half = rem & 1;
    int qb   = 30 + qbh;
    int base_t = (qbh * 6 + half * 3) * 8 + h;  // heavy task id for chunk c: base_t + 8*c

    int tid = threadIdx.x;
    int d   = tid & 127;
    int r0  = tid >> 7;
#pragma unroll
    for (int itr = 0; itr < 4; ++itr) {
        int row = rg * 8 + r0 + itr * 2;
        float l = pL[(base_t + 0) * 64 + row] + pL[(base_t + 8) * 64 + row] + pL[(base_t + 16) * 64 + row];
        float acc = pO[(size_t)(base_t + 0) * 8192 + row * 128 + d]
                  + pO[(size_t)(base_t + 8) * 8192 + row * 128 + d]
                  + pO[(size_t)(base_t + 16) * 8192 + row * 128 + d];
        int qrow = qb * 128 + half * 64 + row;
        out[((size_t)orig_pos(qrow) * 8 + h) * 128 + d] = acc / l;
    }
}

extern "C" void kernel_launch(void* const* d_in, const int* in_sizes, int n_in,
                              void* d_out, int out_size, void* d_ws, size_t ws_size,
                              hipStream_t stream) {
    const float* q = (const float*)d_in[0];
    const float* k = (const float*)d_in[1];
    const float* v = (const float*)d_in[2];
    float* out = (float*)d_out;

    char* w = (char*)d_ws;
    short* Kc  = (short*)(w);                 // 10,027,008 B
    short* Vt  = (short*)(w + 10027008);      // 10,027,008 B (VROW=68)
    float* qp  = (float*)(w + 20054016);      // 147,456 B
    float* kp  = (float*)(w + 20201472);      // 147,456 B
    float* pL  = (float*)(w + 20348928);      // 73,728 B
    float* pO  = (float*)(w + 20422656);      // 9,437,184 B  (total ~29.9 MB)

    prep_kernel<<<dim3(576), dim3(256), 0, stream>>>(q, k, v, Kc, (unsigned*)Vt, qp, kp);
    flash_kernel<<<dim3(768), dim3(256), 0, stream>>>(q, Kc, Vt, qp, kp, out, pO, pL);
    combine_kernel<<<dim3(768), dim3(256), 0, stream>>>(pO, pL, out);
}

// Round 2
// 196.399 us; speedup vs baseline: 1.1085x; 1.1085x over previous
//
#include <hip/hip_runtime.h>

// Rainfusion blockwise sparse attention. f32 in/out; fp16 MFMA inside.
// Fixed-m softmax (m=0). Prep pre-permutes K,V to padded fp16 tiles (coalesced).
// R2: flash restructured for LDS-traffic reduction — 2 waves/wg, 32 q-rows/wave,
//     B-fragments (K,V) read ONCE per wave and reused across 2 row-groups
//     (halves duplicated LDS reads). Grid 768 @ 3 wg/CU, single-buffer, R0 sync.
//     Q pre-scaled by softmax scale at fp16 cvt. Prep split: conv|pooled wgs (1152).

typedef __attribute__((ext_vector_type(8))) _Float16 half8;
typedef __attribute__((ext_vector_type(4))) _Float16 half4;
typedef __attribute__((ext_vector_type(4))) float float4v;

#define KROW 136   // shorts per K row: 128 dims + 8 pad
#define VROW 68    // shorts per V^T row: 64 toks + 4 pad
#define PPROW 68   // shorts per P row: 64 toks + 4 pad

__device__ __forceinline__ int orig_pos(int j) {
    if (j >= 3840) return (j < 4224) ? (j - 3840) : j;
    int blk = j >> 7;
    int r   = j & 127;
    int f   = blk / 6;
    int rem = blk - f * 6;
    int b2  = rem / 3;
    int e   = rem - b2 * 3;
    int a   = r >> 6;
    int c   = (r >> 3) & 7;
    int g   = r & 7;
    return 384 + (f * 2 + a) * 384 + (b2 * 8 + c) * 24 + e * 8 + g;
}

__device__ __forceinline__ void cp16(const void* g, void* l) {
    __builtin_amdgcn_global_load_lds((const __attribute__((address_space(1))) void*)g,
                                     (__attribute__((address_space(3))) void*)l, 16, 0, 0);
}

// ---------------- prep: grid 1152. bx<576: conv+transpose. bx>=576: pooled mean. ----------------
__global__ __launch_bounds__(256) void prep_kernel(const float* __restrict__ q,
                                                   const float* __restrict__ k,
                                                   const float* __restrict__ v,
                                                   short* __restrict__ Kc,
                                                   unsigned* __restrict__ Vt32,
                                                   float* __restrict__ qp,
                                                   float* __restrict__ kp) {
    __shared__ short Vs[64 * KROW];
    __shared__ float Rs[8 * 128];
    int bx  = blockIdx.x;
    int tid = threadIdx.x;

    if (bx < 576) {  // conv: 64 toks -> Kc fp16 + Vs (LDS); then V^T transpose -> Vt
        int sub = bx & 1;
        int kb  = (bx >> 1) % 36;
        int h   = bx / 72;

        int lr = tid >> 3;             // row group 0..31
        int ld = (tid & 7) << 2;       // float offset 0..28
#pragma unroll
        for (int pass = 0; pass < 2; ++pass) {
            int lt  = pass * 32 + lr;  // local tok 0..63
            int tok = sub * 64 + lt;
            int op  = orig_pos(kb * 128 + tok);
            const float* kr = k + ((size_t)op * 8 + h) * 128;
            const float* vr = v + ((size_t)op * 8 + h) * 128;
            short* ko = Kc + ((size_t)(h * 36 + kb) * 128 + tok) * KROW;
#pragma unroll
            for (int j = 0; j < 4; ++j) {
                int d = ld + j * 32;
                float4v xk = *reinterpret_cast<const float4v*>(kr + d);
                float4v xv = *reinterpret_cast<const float4v*>(vr + d);
                half4 hk, hv;
#pragma unroll
                for (int i = 0; i < 4; ++i) { hk[i] = (_Float16)xk[i]; hv[i] = (_Float16)xv[i]; }
                *reinterpret_cast<half4*>(ko + d) = hk;
                *reinterpret_cast<half4*>(&Vs[lt * KROW + d]) = hv;
            }
        }
        __syncthreads();

        { // V^T -> Vt [h][kb][sub][dim][VROW/2], dword-packed token pairs
            const unsigned short* Vsu = (const unsigned short*)Vs;
            unsigned* vo = Vt32 + (size_t)((h * 36 + kb) * 2 + sub) * 128 * (VROW / 2);
#pragma unroll
            for (int it = 0; it < 16; ++it) {
                int i   = it * 256 + tid;
                int tw  = i & 31;
                int dim = i >> 5;
                unsigned lo = Vsu[(2 * tw) * KROW + dim];
                unsigned hi = Vsu[(2 * tw + 1) * KROW + dim];
                vo[dim * (VROW / 2) + tw] = (hi << 16) | lo;
            }
        }
    } else {  // pooled mean over the full 128-token block: sub=0 -> K, sub=1 -> Q
        int bx2 = bx - 576;
        int sub = bx2 & 1;
        int kb  = (bx2 >> 1) % 36;
        int h   = bx2 / 72;

        const float* arr = sub ? q : k;
        int dq = (tid & 31) << 2;
        int g  = tid >> 5;
        float4v acc = {0.f, 0.f, 0.f, 0.f};
#pragma unroll
        for (int it = 0; it < 16; ++it) {
            int t  = g + it * 8;
            int op = orig_pos(kb * 128 + t);
            float4v x = *reinterpret_cast<const float4v*>(arr + ((size_t)op * 8 + h) * 128 + dq);
            acc[0] += x[0]; acc[1] += x[1]; acc[2] += x[2]; acc[3] += x[3];
        }
#pragma unroll
        for (int i = 0; i < 4; ++i) Rs[g * 128 + dq + i] = acc[i];
        __syncthreads();

        if (tid < 128) {
            float s = 0.f;
#pragma unroll
            for (int g2 = 0; g2 < 8; ++g2) s += Rs[g2 * 128 + tid];
            float* outp = sub ? qp : kp;
            outp[(h * 36 + kb) * 128 + tid] = s * (1.f / 128.f);
        }
    }
}

// ---------------- flash ----------------
// grid 768, 128 threads (2 waves), each wave owns 32 q-rows (2 row-groups).
// h = blockIdx%8 (XCD affinity). 0..287 heavy, 288..767 light (self-select, wave 0).
// LDS ~43.8KB -> 3 wg/CU, all 768 co-resident. K/V B-frags read once, reused 2x.
__global__ __launch_bounds__(128, 2) void flash_kernel(const float* __restrict__ q,
                                                       const short* __restrict__ Kc,
                                                       const short* __restrict__ Vt,
                                                       const float* __restrict__ qp,
                                                       const float* __restrict__ kp,
                                                       float* __restrict__ out,
                                                       float* __restrict__ pO,
                                                       float* __restrict__ pL) {
    __shared__ __align__(16) short Ks[64 * KROW];     // 17408 B
    __shared__ __align__(16) short Vsh[128 * VROW];   // 17408 B
    __shared__ __align__(16) short Ph[2 * 32 * PPROW];// 8704 B
    __shared__ int Ls[40];

    int t = blockIdx.x;
    int h, qb, half, nkb = 0, kbase = 0, pidx = -1;
    if (t < 288) {
        h = t & 7;
        int rest = t >> 3;             // 0..35 = qbh*6 + half*3 + chunk
        int qbh = rest / 6, r2 = rest % 6;
        half = r2 / 3;
        int chunk = r2 % 3;
        qb = 30 + qbh; nkb = 12; kbase = chunk * 12; pidx = t;
    } else {
        int t2 = t - 288;
        h = t2 & 7;
        int rest = t2 >> 3;            // 0..59 = qb*2 + half
        qb = rest >> 1; half = rest & 1;
    }

    int tid = threadIdx.x, wave = tid >> 6, lane = tid & 63;
    int m16 = lane & 15, quad = lane >> 4;

    constexpr float kScale = 0.08838834764831845f * 1.4426950408889634f;

    // Q A-frags: 2 row-groups per wave, pre-scaled by softmax scale
    half8 aq[2][4];
#pragma unroll
    for (int rg = 0; rg < 2; ++rg) {
        int qrow_frag = qb * 128 + half * 64 + wave * 32 + rg * 16 + m16;
        const float* qrp = q + ((size_t)orig_pos(qrow_frag) * 8 + h) * 128;
#pragma unroll
        for (int kc = 0; kc < 4; ++kc) {
            float4v x0 = *reinterpret_cast<const float4v*>(qrp + kc * 32 + quad * 8);
            float4v x1 = *reinterpret_cast<const float4v*>(qrp + kc * 32 + quad * 8 + 4);
#pragma unroll
            for (int j = 0; j < 4; ++j) {
                aq[rg][kc][j]     = (_Float16)(x0[j] * kScale);
                aq[rg][kc][4 + j] = (_Float16)(x1[j] * kScale);
            }
        }
    }

    // fused selection (light tasks only; wave 0) — identical arithmetic
    if (pidx < 0 && wave == 0) {
        float s = -1e30f;
        if (lane < 36) {
            const float4v* qv = (const float4v*)(qp + (h * 36 + qb) * 128);
            const float4v* kv = (const float4v*)(kp + (h * 36 + lane) * 128);
            float acc = 0.f;
            for (int i = 0; i < 32; ++i) {
                float4v a = qv[i], b = kv[i];
                acc += a[0] * b[0] + a[1] * b[1] + a[2] * b[2] + a[3] * b[3];
            }
            s = acc;
        }
        float tmp = s;
        float thr = 0.f;
        for (int i = 0; i < 4; ++i) {
            float mx = tmp;
            for (int off = 1; off < 64; off <<= 1) mx = fmaxf(mx, __shfl_xor(mx, off));
            thr = mx;
            unsigned long long bal = __ballot(tmp == mx);
            int low = __ffsll(bal) - 1;
            if (lane == low) tmp = -3e38f;
        }
        bool keep = (lane < 36) && ((s >= thr) || (lane >= 30));
        unsigned long long mk = __ballot(keep);
        if (lane == 0) Ls[0] = __popcll(mk);
        if (keep) {
            int pos = __popcll(mk & ((1ull << lane) - 1ull));
            Ls[1 + pos] = lane;
        }
    }
    __syncthreads();
    if (pidx < 0) nkb = Ls[0];

    float l_r[2][4];
    float4v o[2][8];
#pragma unroll
    for (int rg = 0; rg < 2; ++rg) {
#pragma unroll
        for (int r = 0; r < 4; ++r) l_r[rg][r] = 0.f;
#pragma unroll
        for (int dt = 0; dt < 8; ++dt) { o[rg][dt][0] = 0.f; o[rg][dt][1] = 0.f; o[rg][dt][2] = 0.f; o[rg][dt][3] = 0.f; }
    }

    short* Phw = Ph + wave * (32 * PPROW);

    int ntile = nkb * 2;
    for (int it = 0; it < ntile; ++it) {
        int kb  = (pidx >= 0) ? (kbase + (it >> 1)) : Ls[1 + (it >> 1)];
        int sub = it & 1;
        const char* gK = (const char*)(Kc + ((size_t)((h * 36 + kb) * 128) + sub * 64) * KROW);
        const char* gV = (const char*)(Vt + (size_t)((h * 36 + kb) * 2 + sub) * 128 * VROW);

        __syncthreads();
        {   // 34 x 1KB chunks (17 K + 17 V), 17 per wave
            char* lK = (char*)Ks;
            char* lV = (char*)Vsh;
            int off = lane * 16;
            for (int c = wave; c < 34; c += 2) {
                if (c < 17) cp16(gK + c * 1024 + off, lK + c * 1024 + off);
                else        cp16(gV + (c - 17) * 1024 + off, lV + (c - 17) * 1024 + off);
            }
        }
        __syncthreads();

        // S = Q K^T (64 tokens, 2 row-groups share each bk read)
        float4v sacc[2][4];
#pragma unroll
        for (int rg = 0; rg < 2; ++rg)
#pragma unroll
            for (int nt = 0; nt < 4; ++nt) { sacc[rg][nt][0] = 0.f; sacc[rg][nt][1] = 0.f; sacc[rg][nt][2] = 0.f; sacc[rg][nt][3] = 0.f; }
#pragma unroll
        for (int nt = 0; nt < 4; ++nt)
#pragma unroll
            for (int kc = 0; kc < 4; ++kc) {
                half8 bk = *reinterpret_cast<const half8*>(&Ks[(nt * 16 + m16) * KROW + kc * 32 + quad * 8]);
                sacc[0][nt] = __builtin_amdgcn_mfma_f32_16x16x32_f16(aq[0][kc], bk, sacc[0][nt], 0, 0, 0);
                sacc[1][nt] = __builtin_amdgcn_mfma_f32_16x16x32_f16(aq[1][kc], bk, sacc[1][nt], 0, 0, 0);
            }

        // fixed-m softmax: p = 2^(s) (scale pre-folded into Q); lane-local l accum
#pragma unroll
        for (int rg = 0; rg < 2; ++rg)
#pragma unroll
            for (int r = 0; r < 4; ++r) {
                float p0 = exp2f(sacc[rg][0][r]);
                float p1 = exp2f(sacc[rg][1][r]);
                float p2 = exp2f(sacc[rg][2][r]);
                float p3 = exp2f(sacc[rg][3][r]);
                sacc[rg][0][r] = p0; sacc[rg][1][r] = p1; sacc[rg][2][r] = p2; sacc[rg][3][r] = p3;
                l_r[rg][r] += (p0 + p1) + (p2 + p3);
            }

        // P -> fp16 LDS (wave-private; C-layout write, A-layout read)
#pragma unroll
        for (int rg = 0; rg < 2; ++rg)
#pragma unroll
            for (int nt = 0; nt < 4; ++nt)
#pragma unroll
                for (int r = 0; r < 4; ++r) {
                    union { _Float16 hf; short s; } cv;
                    cv.hf = (_Float16)sacc[rg][nt][r];
                    Phw[(rg * 16 + quad * 4 + r) * PPROW + nt * 16 + m16] = cv.s;
                }
        half8 ap[2][2];
#pragma unroll
        for (int rg = 0; rg < 2; ++rg) {
            ap[rg][0] = *reinterpret_cast<const half8*>(&Phw[(rg * 16 + m16) * PPROW + quad * 8]);
            ap[rg][1] = *reinterpret_cast<const half8*>(&Phw[(rg * 16 + m16) * PPROW + 32 + quad * 8]);
        }

        // O += P V (2 row-groups share each bv read)
#pragma unroll
        for (int dt = 0; dt < 8; ++dt) {
            half8 bv0 = *reinterpret_cast<const half8*>(&Vsh[(dt * 16 + m16) * VROW + quad * 8]);
            half8 bv1 = *reinterpret_cast<const half8*>(&Vsh[(dt * 16 + m16) * VROW + 32 + quad * 8]);
#pragma unroll
            for (int rg = 0; rg < 2; ++rg) {
                float4v oc = o[rg][dt];
                oc = __builtin_amdgcn_mfma_f32_16x16x32_f16(ap[rg][0], bv0, oc, 0, 0, 0);
                oc = __builtin_amdgcn_mfma_f32_16x16x32_f16(ap[rg][1], bv1, oc, 0, 0, 0);
                o[rg][dt] = oc;
            }
        }
    }

    // epilogue: reduce l across the quad-group's 16 lanes
#pragma unroll
    for (int rg = 0; rg < 2; ++rg)
#pragma unroll
        for (int r = 0; r < 4; ++r)
            for (int sh = 1; sh < 16; sh <<= 1) l_r[rg][r] += __shfl_xor(l_r[rg][r], sh);

    if (pidx >= 0) {
        float* po = pO + (size_t)pidx * 8192;
#pragma unroll
        for (int rg = 0; rg < 2; ++rg)
#pragma unroll
            for (int r = 0; r < 4; ++r) {
                int row = wave * 32 + rg * 16 + quad * 4 + r;
#pragma unroll
                for (int dt = 0; dt < 8; ++dt)
                    po[row * 128 + dt * 16 + m16] = o[rg][dt][r];
                if (m16 == 0) pL[pidx * 64 + row] = l_r[rg][r];
            }
    } else {
#pragma unroll
        for (int rg = 0; rg < 2; ++rg)
#pragma unroll
            for (int r = 0; r < 4; ++r) {
                int qrow = qb * 128 + half * 64 + wave * 32 + rg * 16 + quad * 4 + r;
                size_t base = ((size_t)orig_pos(qrow) * 8 + h) * 128;
                float inv = 1.f / l_r[rg][r];
#pragma unroll
                for (int dt = 0; dt < 8; ++dt)
                    out[base + dt * 16 + m16] = o[rg][dt][r] * inv;
            }
    }
}

// ---------------- combine (heavy only; fixed-m partials sum linearly) ----------------
__global__ void combine_kernel(const float* __restrict__ pO, const float* __restrict__ pL,
                               float* __restrict__ out) {
    int gb = blockIdx.x;             // 768
    int g  = gb >> 3;                // 96 = (h,qbh,half)
    int rg = gb & 7;                 // row-group: 8 rows each
    int h    = g / 12;
    int rem  = g % 12;
    int qbh  = rem >> 1;
    int half = rem & 1;
    int qb   = 30 + qbh;
    int base_t = (qbh * 6 + half * 3) * 8 + h;  // heavy task id for chunk c: base_t + 8*c

    int tid = threadIdx.x;
    int d   = tid & 127;
    int r0  = tid >> 7;
#pragma unroll
    for (int itr = 0; itr < 4; ++itr) {
        int row = rg * 8 + r0 + itr * 2;
        float l = pL[(base_t + 0) * 64 + row] + pL[(base_t + 8) * 64 + row] + pL[(base_t + 16) * 64 + row];
        float acc = pO[(size_t)(base_t + 0) * 8192 + row * 128 + d]
                  + pO[(size_t)(base_t + 8) * 8192 + row * 128 + d]
                  + pO[(size_t)(base_t + 16) * 8192 + row * 128 + d];
        int qrow = qb * 128 + half * 64 + row;
        out[((size_t)orig_pos(qrow) * 8 + h) * 128 + d] = acc / l;
    }
}

extern "C" void kernel_launch(void* const* d_in, const int* in_sizes, int n_in,
                              void* d_out, int out_size, void* d_ws, size_t ws_size,
                              hipStream_t stream) {
    const float* q = (const float*)d_in[0];
    const float* k = (const float*)d_in[1];
    const float* v = (const float*)d_in[2];
    float* out = (float*)d_out;

    char* w = (char*)d_ws;
    short* Kc  = (short*)(w);                 // 10,027,008 B
    short* Vt  = (short*)(w + 10027008);      // 10,027,008 B (VROW=68)
    float* qp  = (float*)(w + 20054016);      // 147,456 B
    float* kp  = (float*)(w + 20201472);      // 147,456 B
    float* pL  = (float*)(w + 20348928);      // 73,728 B
    float* pO  = (float*)(w + 20422656);      // 9,437,184 B  (total ~29.9 MB)

    prep_kernel<<<dim3(1152), dim3(256), 0, stream>>>(q, k, v, Kc, (unsigned*)Vt, qp, kp);
    flash_kernel<<<dim3(768), dim3(128), 0, stream>>>(q, Kc, Vt, qp, kp, out, pO, pL);
    combine_kernel<<<dim3(768), dim3(256), 0, stream>>>(pO, pL, out);
}

// Round 4
// 169.682 us; speedup vs baseline: 1.2831x; 1.1575x over previous
//
#include <hip/hip_runtime.h>

// Rainfusion blockwise sparse attention. f32 in/out; fp16 MFMA inside.
// Fixed-m softmax (m=0). Prep pre-permutes K,V to padded fp16 tiles (coalesced).
// R3 (resubmit; prior run died to container infra, not the kernel):
//     token-split waves — 4 waves/wg, each wave = (rowhalf, tokhalf) 32 rows x 32 toks.
//     K/V B-frags read once per wave, reused across 2 row-groups; per-wave LDS reads
//     34->18 b128 while keeping 12 waves/CU (3 wg/CU). Cross-wave O/l reduction at
//     epilogue through dead Ks/Vsh. Q pre-scaled at fp16 cvt. VROW=72 (16B-aligned),
//     PPROW=40. Plain R0 sync. prep split + combine regrid kept from R2.

typedef __attribute__((ext_vector_type(8))) _Float16 half8;
typedef __attribute__((ext_vector_type(4))) _Float16 half4;
typedef __attribute__((ext_vector_type(4))) float float4v;

#define KROW 136   // shorts per K row: 128 dims + 8 pad
#define VROW 72    // shorts per V^T row: 64 toks + 8 pad (144B rows, 16B-aligned)
#define PPROW 40   // shorts per P row: 32 toks + 8 pad (80B rows, 16B-aligned)

__device__ __forceinline__ int orig_pos(int j) {
    if (j >= 3840) return (j < 4224) ? (j - 3840) : j;
    int blk = j >> 7;
    int r   = j & 127;
    int f   = blk / 6;
    int rem = blk - f * 6;
    int b2  = rem / 3;
    int e   = rem - b2 * 3;
    int a   = r >> 6;
    int c   = (r >> 3) & 7;
    int g   = r & 7;
    return 384 + (f * 2 + a) * 384 + (b2 * 8 + c) * 24 + e * 8 + g;
}

__device__ __forceinline__ void cp16(const void* g, void* l) {
    __builtin_amdgcn_global_load_lds((const __attribute__((address_space(1))) void*)g,
                                     (__attribute__((address_space(3))) void*)l, 16, 0, 0);
}

// ---------------- prep: grid 1152. bx<576: conv+transpose. bx>=576: pooled mean. ----------------
__global__ __launch_bounds__(256) void prep_kernel(const float* __restrict__ q,
                                                   const float* __restrict__ k,
                                                   const float* __restrict__ v,
                                                   short* __restrict__ Kc,
                                                   unsigned* __restrict__ Vt32,
                                                   float* __restrict__ qp,
                                                   float* __restrict__ kp) {
    __shared__ short Vs[64 * KROW];
    __shared__ float Rs[8 * 128];
    int bx  = blockIdx.x;
    int tid = threadIdx.x;

    if (bx < 576) {  // conv: 64 toks -> Kc fp16 + Vs (LDS); then V^T transpose -> Vt
        int sub = bx & 1;
        int kb  = (bx >> 1) % 36;
        int h   = bx / 72;

        int lr = tid >> 3;             // row group 0..31
        int ld = (tid & 7) << 2;       // float offset 0..28
#pragma unroll
        for (int pass = 0; pass < 2; ++pass) {
            int lt  = pass * 32 + lr;  // local tok 0..63
            int tok = sub * 64 + lt;
            int op  = orig_pos(kb * 128 + tok);
            const float* kr = k + ((size_t)op * 8 + h) * 128;
            const float* vr = v + ((size_t)op * 8 + h) * 128;
            short* ko = Kc + ((size_t)(h * 36 + kb) * 128 + tok) * KROW;
#pragma unroll
            for (int j = 0; j < 4; ++j) {
                int d = ld + j * 32;
                float4v xk = *reinterpret_cast<const float4v*>(kr + d);
                float4v xv = *reinterpret_cast<const float4v*>(vr + d);
                half4 hk, hv;
#pragma unroll
                for (int i = 0; i < 4; ++i) { hk[i] = (_Float16)xk[i]; hv[i] = (_Float16)xv[i]; }
                *reinterpret_cast<half4*>(ko + d) = hk;
                *reinterpret_cast<half4*>(&Vs[lt * KROW + d]) = hv;
            }
        }
        __syncthreads();

        { // V^T -> Vt [h][kb][sub][dim][VROW/2], dword-packed token pairs
            const unsigned short* Vsu = (const unsigned short*)Vs;
            unsigned* vo = Vt32 + (size_t)((h * 36 + kb) * 2 + sub) * 128 * (VROW / 2);
#pragma unroll
            for (int it = 0; it < 16; ++it) {
                int i   = it * 256 + tid;
                int tw  = i & 31;
                int dim = i >> 5;
                unsigned lo = Vsu[(2 * tw) * KROW + dim];
                unsigned hi = Vsu[(2 * tw + 1) * KROW + dim];
                vo[dim * (VROW / 2) + tw] = (hi << 16) | lo;
            }
        }
    } else {  // pooled mean over the full 128-token block: sub=0 -> K, sub=1 -> Q
        int bx2 = bx - 576;
        int sub = bx2 & 1;
        int kb  = (bx2 >> 1) % 36;
        int h   = bx2 / 72;

        const float* arr = sub ? q : k;
        int dq = (tid & 31) << 2;
        int g  = tid >> 5;
        float4v acc = {0.f, 0.f, 0.f, 0.f};
#pragma unroll
        for (int it = 0; it < 16; ++it) {
            int t  = g + it * 8;
            int op = orig_pos(kb * 128 + t);
            float4v x = *reinterpret_cast<const float4v*>(arr + ((size_t)op * 8 + h) * 128 + dq);
            acc[0] += x[0]; acc[1] += x[1]; acc[2] += x[2]; acc[3] += x[3];
        }
#pragma unroll
        for (int i = 0; i < 4; ++i) Rs[g * 128 + dq + i] = acc[i];
        __syncthreads();

        if (tid < 128) {
            float s = 0.f;
#pragma unroll
            for (int g2 = 0; g2 < 8; ++g2) s += Rs[g2 * 128 + tid];
            float* outp = sub ? qp : kp;
            outp[(h * 36 + kb) * 128 + tid] = s * (1.f / 128.f);
        }
    }
}

// ---------------- flash ----------------
// grid 768, 256 threads (4 waves). wave = (rh = wave&1, th = wave>>1):
// rows rh*32 + rg*16 + quad*4 + r, tokens th*32 + [0..31]. 3 wg/CU = 12 waves/CU.
// h = blockIdx%8 (XCD affinity). 0..287 heavy, 288..767 light (self-select, wave 0).
__global__ __launch_bounds__(256, 3) void flash_kernel(const float* __restrict__ q,
                                                       const short* __restrict__ Kc,
                                                       const short* __restrict__ Vt,
                                                       const float* __restrict__ qp,
                                                       const float* __restrict__ kp,
                                                       float* __restrict__ out,
                                                       float* __restrict__ pO,
                                                       float* __restrict__ pL) {
    __shared__ __align__(16) short Ks[64 * KROW];      // 17408 B (also f32 O-red rh=0: 16896B)
    __shared__ __align__(16) short Vsh[128 * VROW];    // 18432 B (also f32 O-red rh=1)
    __shared__ __align__(16) short Ph[4 * 32 * PPROW]; // 10240 B
    __shared__ int Ls[40];
    __shared__ float Lf[64];

    int t = blockIdx.x;
    int h, qb, half, nkb = 0, kbase = 0, pidx = -1;
    if (t < 288) {
        h = t & 7;
        int rest = t >> 3;             // 0..35 = qbh*6 + half*3 + chunk
        int qbh = rest / 6, r2 = rest % 6;
        half = r2 / 3;
        int chunk = r2 % 3;
        qb = 30 + qbh; nkb = 12; kbase = chunk * 12; pidx = t;
    } else {
        int t2 = t - 288;
        h = t2 & 7;
        int rest = t2 >> 3;            // 0..59 = qb*2 + half
        qb = rest >> 1; half = rest & 1;
    }

    int tid = threadIdx.x, wave = tid >> 6, lane = tid & 63;
    int m16 = lane & 15, quad = lane >> 4;
    int rh = wave & 1, th = wave >> 1;

    constexpr float kScale = 0.08838834764831845f * 1.4426950408889634f;

    // Q A-frags: 2 row-groups per wave (rows rh*32 + rg*16 + m16), pre-scaled
    half8 aq[2][4];
#pragma unroll
    for (int rg = 0; rg < 2; ++rg) {
        int qrow_frag = qb * 128 + half * 64 + rh * 32 + rg * 16 + m16;
        const float* qrp = q + ((size_t)orig_pos(qrow_frag) * 8 + h) * 128;
#pragma unroll
        for (int kc = 0; kc < 4; ++kc) {
            float4v x0 = *reinterpret_cast<const float4v*>(qrp + kc * 32 + quad * 8);
            float4v x1 = *reinterpret_cast<const float4v*>(qrp + kc * 32 + quad * 8 + 4);
#pragma unroll
            for (int j = 0; j < 4; ++j) {
                aq[rg][kc][j]     = (_Float16)(x0[j] * kScale);
                aq[rg][kc][4 + j] = (_Float16)(x1[j] * kScale);
            }
        }
    }

    // fused selection (light tasks only; wave 0) — identical arithmetic
    if (pidx < 0 && wave == 0) {
        float s = -1e30f;
        if (lane < 36) {
            const float4v* qv = (const float4v*)(qp + (h * 36 + qb) * 128);
            const float4v* kv = (const float4v*)(kp + (h * 36 + lane) * 128);
            float acc = 0.f;
            for (int i = 0; i < 32; ++i) {
                float4v a = qv[i], b = kv[i];
                acc += a[0] * b[0] + a[1] * b[1] + a[2] * b[2] + a[3] * b[3];
            }
            s = acc;
        }
        float tmp = s;
        float thr = 0.f;
        for (int i = 0; i < 4; ++i) {
            float mx = tmp;
            for (int off = 1; off < 64; off <<= 1) mx = fmaxf(mx, __shfl_xor(mx, off));
            thr = mx;
            unsigned long long bal = __ballot(tmp == mx);
            int low = __ffsll(bal) - 1;
            if (lane == low) tmp = -3e38f;
        }
        bool keep = (lane < 36) && ((s >= thr) || (lane >= 30));
        unsigned long long mk = __ballot(keep);
        if (lane == 0) Ls[0] = __popcll(mk);
        if (keep) {
            int pos = __popcll(mk & ((1ull << lane) - 1ull));
            Ls[1 + pos] = lane;
        }
    }
    __syncthreads();
    if (pidx < 0) nkb = Ls[0];

    float l_r[2][4];
    float4v o[2][8];
#pragma unroll
    for (int rg = 0; rg < 2; ++rg) {
#pragma unroll
        for (int r = 0; r < 4; ++r) l_r[rg][r] = 0.f;
#pragma unroll
        for (int dt = 0; dt < 8; ++dt) { o[rg][dt][0] = 0.f; o[rg][dt][1] = 0.f; o[rg][dt][2] = 0.f; o[rg][dt][3] = 0.f; }
    }

    short* Phw = Ph + wave * (32 * PPROW);

    int ntile = nkb * 2;
    for (int it = 0; it < ntile; ++it) {
        int kb  = (pidx >= 0) ? (kbase + (it >> 1)) : Ls[1 + (it >> 1)];
        int sub = it & 1;
        const char* gK = (const char*)(Kc + ((size_t)((h * 36 + kb) * 128) + sub * 64) * KROW);
        const char* gV = (const char*)(Vt + (size_t)((h * 36 + kb) * 2 + sub) * 128 * VROW);

        __syncthreads();
        {   // 35 x 1KB chunks (17 K + 18 V)
            char* lK = (char*)Ks;
            char* lV = (char*)Vsh;
            int off = lane * 16;
            for (int c = wave; c < 35; c += 4) {
                if (c < 17) cp16(gK + c * 1024 + off, lK + c * 1024 + off);
                else        cp16(gV + (c - 17) * 1024 + off, lV + (c - 17) * 1024 + off);
            }
        }
        __syncthreads();

        // S = Q K^T (this wave's 32 tokens; bk shared across 2 row-groups)
        float4v sacc[2][2];
#pragma unroll
        for (int rg = 0; rg < 2; ++rg)
#pragma unroll
            for (int nt = 0; nt < 2; ++nt) { sacc[rg][nt][0] = 0.f; sacc[rg][nt][1] = 0.f; sacc[rg][nt][2] = 0.f; sacc[rg][nt][3] = 0.f; }
#pragma unroll
        for (int nt = 0; nt < 2; ++nt)
#pragma unroll
            for (int kc = 0; kc < 4; ++kc) {
                half8 bk = *reinterpret_cast<const half8*>(&Ks[(th * 32 + nt * 16 + m16) * KROW + kc * 32 + quad * 8]);
                sacc[0][nt] = __builtin_amdgcn_mfma_f32_16x16x32_f16(aq[0][kc], bk, sacc[0][nt], 0, 0, 0);
                sacc[1][nt] = __builtin_amdgcn_mfma_f32_16x16x32_f16(aq[1][kc], bk, sacc[1][nt], 0, 0, 0);
            }

        // fixed-m softmax: p = 2^s (scale pre-folded into Q); lane-local l accum
#pragma unroll
        for (int rg = 0; rg < 2; ++rg)
#pragma unroll
            for (int r = 0; r < 4; ++r) {
                float p0 = exp2f(sacc[rg][0][r]);
                float p1 = exp2f(sacc[rg][1][r]);
                sacc[rg][0][r] = p0; sacc[rg][1][r] = p1;
                l_r[rg][r] += p0 + p1;
            }

        // P -> fp16 LDS (wave-private; C-layout write, A-layout read; local 32 cols)
#pragma unroll
        for (int rg = 0; rg < 2; ++rg)
#pragma unroll
            for (int nt = 0; nt < 2; ++nt)
#pragma unroll
                for (int r = 0; r < 4; ++r) {
                    union { _Float16 hf; short s; } cv;
                    cv.hf = (_Float16)sacc[rg][nt][r];
                    Phw[(rg * 16 + quad * 4 + r) * PPROW + nt * 16 + m16] = cv.s;
                }
        half8 ap[2];
#pragma unroll
        for (int rg = 0; rg < 2; ++rg)
            ap[rg] = *reinterpret_cast<const half8*>(&Phw[(rg * 16 + m16) * PPROW + quad * 8]);

        // O += P V over this wave's 32 tokens (bv shared across 2 row-groups)
#pragma unroll
        for (int dt = 0; dt < 8; ++dt) {
            half8 bv = *reinterpret_cast<const half8*>(&Vsh[(dt * 16 + m16) * VROW + th * 32 + quad * 8]);
            o[0][dt] = __builtin_amdgcn_mfma_f32_16x16x32_f16(ap[0], bv, o[0][dt], 0, 0, 0);
            o[1][dt] = __builtin_amdgcn_mfma_f32_16x16x32_f16(ap[1], bv, o[1][dt], 0, 0, 0);
        }
    }

    // reduce l across the 16 cols held per lane-group
#pragma unroll
    for (int rg = 0; rg < 2; ++rg)
#pragma unroll
        for (int r = 0; r < 4; ++r)
            for (int sh = 1; sh < 16; sh <<= 1) l_r[rg][r] += __shfl_xor(l_r[rg][r], sh);

    // cross-wave reduction over token halves (th=1 -> LDS, th=0 adds + writes out)
    __syncthreads();   // all waves done with Ks/Vsh
    {
        float* red = rh ? (float*)Vsh : (float*)Ks;   // 32 rows x stride 132 floats = 16896B
        if (th == 1) {
#pragma unroll
            for (int rg = 0; rg < 2; ++rg) {
#pragma unroll
                for (int dt = 0; dt < 8; ++dt)
#pragma unroll
                    for (int r = 0; r < 4; ++r)
                        red[(rg * 16 + quad * 4 + r) * 132 + dt * 16 + m16] = o[rg][dt][r];
                if (m16 == 0)
#pragma unroll
                    for (int r = 0; r < 4; ++r)
                        Lf[rh * 32 + rg * 16 + quad * 4 + r] = l_r[rg][r];
            }
        }
        __syncthreads();
        if (th == 0) {
#pragma unroll
            for (int rg = 0; rg < 2; ++rg)
#pragma unroll
                for (int dt = 0; dt < 8; ++dt)
#pragma unroll
                    for (int r = 0; r < 4; ++r)
                        o[rg][dt][r] += red[(rg * 16 + quad * 4 + r) * 132 + dt * 16 + m16];

            if (pidx >= 0) {
                float* po = pO + (size_t)pidx * 8192;
#pragma unroll
                for (int rg = 0; rg < 2; ++rg)
#pragma unroll
                    for (int r = 0; r < 4; ++r) {
                        int row = rh * 32 + rg * 16 + quad * 4 + r;
                        float lt2 = l_r[rg][r] + Lf[row];
#pragma unroll
                        for (int dt = 0; dt < 8; ++dt)
                            po[row * 128 + dt * 16 + m16] = o[rg][dt][r];
                        if (m16 == 0) pL[pidx * 64 + row] = lt2;
                    }
            } else {
#pragma unroll
                for (int rg = 0; rg < 2; ++rg)
#pragma unroll
                    for (int r = 0; r < 4; ++r) {
                        int row = rh * 32 + rg * 16 + quad * 4 + r;
                        int qrow = qb * 128 + half * 64 + row;
                        size_t base = ((size_t)orig_pos(qrow) * 8 + h) * 128;
                        float inv = 1.f / (l_r[rg][r] + Lf[row]);
#pragma unroll
                        for (int dt = 0; dt < 8; ++dt)
                            out[base + dt * 16 + m16] = o[rg][dt][r] * inv;
                    }
            }
        }
    }
}

// ---------------- combine (heavy only; fixed-m partials sum linearly) ----------------
__global__ void combine_kernel(const float* __restrict__ pO, const float* __restrict__ pL,
                               float* __restrict__ out) {
    int gb = blockIdx.x;             // 768
    int g  = gb >> 3;                // 96 = (h,qbh,half)
    int rg = gb & 7;                 // row-group: 8 rows each
    int h    = g / 12;
    int rem  = g % 12;
    int qbh  = rem >> 1;
    int half = rem & 1;
    int qb   = 30 + qbh;
    int base_t = (qbh * 6 + half * 3) * 8 + h;  // heavy task id for chunk c: base_t + 8*c

    int tid = threadIdx.x;
    int d   = tid & 127;
    int r0  = tid >> 7;
#pragma unroll
    for (int itr = 0; itr < 4; ++itr) {
        int row = rg * 8 + r0 + itr * 2;
        float l = pL[(base_t + 0) * 64 + row] + pL[(base_t + 8) * 64 + row] + pL[(base_t + 16) * 64 + row];
        float acc = pO[(size_t)(base_t + 0) * 8192 + row * 128 + d]
                  + pO[(size_t)(base_t + 8) * 8192 + row * 128 + d]
                  + pO[(size_t)(base_t + 16) * 8192 + row * 128 + d];
        int qrow = qb * 128 + half * 64 + row;
        out[((size_t)orig_pos(qrow) * 8 + h) * 128 + d] = acc / l;
    }
}

extern "C" void kernel_launch(void* const* d_in, const int* in_sizes, int n_in,
                              void* d_out, int out_size, void* d_ws, size_t ws_size,
                              hipStream_t stream) {
    const float* q = (const float*)d_in[0];
    const float* k = (const float*)d_in[1];
    const float* v = (const float*)d_in[2];
    float* out = (float*)d_out;

    char* w = (char*)d_ws;
    short* Kc  = (short*)(w);                 // 10,027,008 B
    short* Vt  = (short*)(w + 10027008);      // 10,616,832 B (VROW=72)
    float* qp  = (float*)(w + 20643840);      // 147,456 B
    float* kp  = (float*)(w + 20791296);      // 147,456 B
    float* pL  = (float*)(w + 20938752);      // 73,728 B
    float* pO  = (float*)(w + 21012480);      // 9,437,184 B  (total ~30.5 MB)

    prep_kernel<<<dim3(1152), dim3(256), 0, stream>>>(q, k, v, Kc, (unsigned*)Vt, qp, kp);
    flash_kernel<<<dim3(768), dim3(256), 0, stream>>>(q, Kc, Vt, qp, kp, out, pO, pL);
    combine_kernel<<<dim3(768), dim3(256), 0, stream>>>(pO, pL, out);
}